// Round 10
// baseline (215.013 us; speedup 1.0000x reference)
//
#include <hip/hip_runtime.h>
#include <hip/hip_bf16.h>
#include <math.h>

#define B_N 4096
#define D_N 768
#define C_N 10

typedef short bf16x8 __attribute__((ext_vector_type(8)));
typedef float f32x4 __attribute__((ext_vector_type(4)));

// ws layout (floats) — NO memset needed: every read location is plain-stored first.
//   [0]            ce partial-sum total   (k_taml helper)
//   [8..18)        counts[10]             (k_taml helper, from labels)
//   [32..7712)     final class sums [10][768]  (k_taml cent-reduce helpers)
//   [8192..8208)   ce partials[16]        (k_prep CE blocks)
//   [8704..9728)   taml partials[1024]    (k_taml gemm blocks, upper-tri slots only)
//   [16384..139264) cent partials [16][10][768] (k_prep cent blocks)
// byte offset 1048576: enorm bf16 [4096*768] (6291456 bytes)
// (harness fill shows d_ws ~256 MB, so this layout is well within ws_size)

typedef __attribute__((address_space(1))) const void gvoid;
typedef __attribute__((address_space(3))) void lvoid;

static __device__ __forceinline__ void gl2lds16(const void* g, void* l) {
    // async global->LDS, 16B per lane, dest = l + lane*16 (wave-uniform l)
    __builtin_amdgcn_global_load_lds((gvoid*)g, (lvoid*)l, 16, 0, 0);
}

// Wait until at most N of this wave's VMEM ops (incl. global_load_lds) are
// outstanding. memory clobber: compiler may not move LDS reads above it.
#define WAIT_VMCNT(N) asm volatile("s_waitcnt vmcnt(" #N ")" ::: "memory")

static __device__ __forceinline__ unsigned short bf16bits(float f, float s) {
    __hip_bfloat16 h = __float2bfloat16(f * s);
    return *(unsigned short*)&h;
}

// ---------------- prep: CE partials | cent partials | row-normalize ----------------
// blocks [0,16): CE partials; [16,64): cent partials (16 row-chunks x 3 col-chunks);
// [64,1088): enorm (wave per row)
__global__ void k_prep(const float* __restrict__ logits,
                       const int* __restrict__ labels,
                       const float* __restrict__ emb,
                       float* __restrict__ ws,
                       __hip_bfloat16* __restrict__ enorm) {
    __shared__ float red[256];
    int bb = blockIdx.x;
    int t = threadIdx.x;

    if (bb < 16) {
        int row = bb * 256 + t;
        int lab = labels[row];
        const float* lp = logits + (size_t)row * C_N;
        float m = lp[0];
#pragma unroll
        for (int c = 1; c < C_N; ++c) m = fmaxf(m, lp[c]);
        float s = 0.f;
#pragma unroll
        for (int c = 0; c < C_N; ++c) s += __expf(lp[c] - m);
        red[t] = (m + __logf(s)) - lp[lab];
        __syncthreads();
        for (int off = 128; off; off >>= 1) {
            if (t < off) red[t] += red[t + off];
            __syncthreads();
        }
        if (t == 0) ws[8192 + bb] = red[0];
    } else if (bb < 64) {
        int chunk = (bb - 16) / 3, bx = (bb - 16) % 3;
        int col = bx * 256 + t;
        int rbase = chunk * 256;
        float a[C_N];
#pragma unroll
        for (int c = 0; c < C_N; ++c) a[c] = 0.f;
        const float* p = emb + (size_t)rbase * D_N + col;
#pragma unroll 4
        for (int rr = 0; rr < 256; ++rr) {
            int lab = labels[rbase + rr];
            float v = p[(size_t)rr * D_N];
#pragma unroll
            for (int c = 0; c < C_N; ++c) a[c] += (lab == c) ? v : 0.f;
        }
        float* part = ws + 16384 + chunk * 7680;
#pragma unroll
        for (int c = 0; c < C_N; ++c) part[c * D_N + col] = a[c];
    } else {
        int w = t >> 6, lane = t & 63;
        int row = (bb - 64) * 4 + w;
        const float4* src = (const float4*)(emb + (size_t)row * D_N);
        float4 x0 = src[lane];
        float4 x1 = src[lane + 64];
        float4 x2 = src[lane + 128];
        float ss = x0.x * x0.x + x0.y * x0.y + x0.z * x0.z + x0.w * x0.w
                 + x1.x * x1.x + x1.y * x1.y + x1.z * x1.z + x1.w * x1.w
                 + x2.x * x2.x + x2.y * x2.y + x2.z * x2.z + x2.w * x2.w;
#pragma unroll
        for (int off = 32; off; off >>= 1) ss += __shfl_xor(ss, off, 64);
        float inv = 1.0f / fmaxf(sqrtf(ss), 1e-12f);
        ushort4* dst = (ushort4*)(enorm + (size_t)row * D_N);
        ushort4 u0, u1, u2;
        u0.x = bf16bits(x0.x, inv); u0.y = bf16bits(x0.y, inv);
        u0.z = bf16bits(x0.z, inv); u0.w = bf16bits(x0.w, inv);
        u1.x = bf16bits(x1.x, inv); u1.y = bf16bits(x1.y, inv);
        u1.z = bf16bits(x1.z, inv); u1.w = bf16bits(x1.w, inv);
        u2.x = bf16bits(x2.x, inv); u2.y = bf16bits(x2.y, inv);
        u2.z = bf16bits(x2.z, inv); u2.w = bf16bits(x2.w, inv);
        dst[lane]       = u0;
        dst[lane + 64]  = u1;
        dst[lane + 128] = u2;
    }
}

// ---------------- fused TAML GEMM: barrier-free wave-private pipeline ----------------
// 128x128 tile, BK=32. Each wave stages ITS OWN 64-row A/B slices (double-buffered,
// 16 KB/wave) via global_load_lds and reads back only its own LDS. RAW hazard is
// wave-local -> no K-loop __syncthreads; explicit s_waitcnt vmcnt(8) keeps the
// next tile's 8 loads in flight while the current tile computes (AITER pattern).
// Early-exit (bj<bi) blocks double as reducers for k_prep partials.
__global__ __launch_bounds__(256) void k_taml(const __hip_bfloat16* __restrict__ E,
                                              const int* __restrict__ labels,
                                              const float* __restrict__ topo,
                                              float* __restrict__ ws) {
    __shared__ __align__(16) __hip_bfloat16 S[4][2][2][2048]; // [wave][A/B][buf][elems] 64KB
    __shared__ int lA[128], lB[128];
    __shared__ float topo_s[C_N * C_N];
    __shared__ float wsum[4];
    __shared__ int hist10[16];

    int bi = blockIdx.y, bj = blockIdx.x;
    int t = threadIdx.x;

    if (bj < bi) {
        // ---- free-labor helper blocks (inputs: k_prep outputs, ready by stream order)
        if (bj < 16 && bi == bj + 1) {
            int g = bj;
            const float* part = ws + 16384;
            for (int idx = g * 480 + t; idx < (g + 1) * 480; idx += 256) {
                float s = 0.f;
#pragma unroll
                for (int p = 0; p < 16; ++p) s += part[p * 7680 + idx];
                ws[32 + idx] = s;
            }
        } else if (bi == 17 && bj == 16) {
            if (t == 0) {
                float s = 0.f;
#pragma unroll
                for (int i = 0; i < 16; ++i) s += ws[8192 + i];
                ws[0] = s;
            }
        } else if (bi == 18 && bj == 17) {
            if (t < 16) hist10[t] = 0;
            __syncthreads();
            for (int i = t; i < B_N; i += 256) atomicAdd(&hist10[labels[i]], 1);
            __syncthreads();
            if (t < C_N) ws[8 + t] = (float)hist10[t];
        }
        return;
    }

    int ib0 = bi * 128, jb0 = bj * 128;
    if (t < 128) lA[t] = labels[ib0 + t];
    else         lB[t - 128] = labels[jb0 + t - 128];
    if (t < C_N * C_N) topo_s[t] = topo[t];

    int w = t >> 6, lane = t & 63;
    int quad = lane >> 4, m16 = lane & 15;
    int wrow = (w >> 1) * 64, wcol = (w & 1) * 64;
    int rL = lane & 15, cL = lane >> 4;   // staging lane map: row-in-chunk, k-slot

    // per-lane global bases: chunk x = rows x*16..x*16+15 of this wave's slice
    const __hip_bfloat16* gA[4];
    const __hip_bfloat16* gB[4];
#pragma unroll
    for (int x = 0; x < 4; ++x) {
        gA[x] = E + (size_t)(ib0 + wrow + x * 16 + rL) * D_N + cL * 8;
        gB[x] = E + (size_t)(jb0 + wcol + x * 16 + rL) * D_N + cL * 8;
    }
    __hip_bfloat16* sA0 = &S[w][0][0][0];
    __hip_bfloat16* sA1 = &S[w][0][1][0];
    __hip_bfloat16* sB0 = &S[w][1][0][0];
    __hip_bfloat16* sB1 = &S[w][1][1][0];

    f32x4 acc[4][4];
    f32x4 z = {0.f, 0.f, 0.f, 0.f};
#pragma unroll
    for (int mt = 0; mt < 4; ++mt)
#pragma unroll
        for (int nt = 0; nt < 4; ++nt) acc[mt][nt] = z;

    // prologue: tile 0 -> buf 0
#pragma unroll
    for (int x = 0; x < 4; ++x) {
        gl2lds16(gA[x], sA0 + x * 512);
        gl2lds16(gB[x], sB0 + x * 512);
    }

#pragma unroll 2
    for (int kt = 0; kt < 23; ++kt) {
        int cur = kt & 1;
        __hip_bfloat16* cA = cur ? sA1 : sA0;
        __hip_bfloat16* cB = cur ? sB1 : sB0;
        __hip_bfloat16* nA = cur ? sA0 : sA1;
        __hip_bfloat16* nB = cur ? sB0 : sB1;
        // issue next tile (8 loads), then wait until only those 8 remain
#pragma unroll
        for (int x = 0; x < 4; ++x) {
            gl2lds16(gA[x] + (kt + 1) * 32, nA + x * 512);
            gl2lds16(gB[x] + (kt + 1) * 32, nB + x * 512);
        }
        WAIT_VMCNT(8);
        bf16x8 af[4], bfr[4];
#pragma unroll
        for (int x = 0; x < 4; ++x) {
            af[x]  = *(const bf16x8*)(cA + x * 512 + quad * 128 + m16 * 8);
            bfr[x] = *(const bf16x8*)(cB + x * 512 + quad * 128 + m16 * 8);
        }
#pragma unroll
        for (int mt = 0; mt < 4; ++mt)
#pragma unroll
            for (int nt = 0; nt < 4; ++nt)
                acc[mt][nt] = __builtin_amdgcn_mfma_f32_16x16x32_bf16(
                    af[mt], bfr[nt], acc[mt][nt], 0, 0, 0);
    }
    {   // tail: tile 23 (in buf 1), nothing left in flight after wait
        WAIT_VMCNT(0);
        bf16x8 af[4], bfr[4];
#pragma unroll
        for (int x = 0; x < 4; ++x) {
            af[x]  = *(const bf16x8*)(sA1 + x * 512 + quad * 128 + m16 * 8);
            bfr[x] = *(const bf16x8*)(sB1 + x * 512 + quad * 128 + m16 * 8);
        }
#pragma unroll
        for (int mt = 0; mt < 4; ++mt)
#pragma unroll
            for (int nt = 0; nt < 4; ++nt)
                acc[mt][nt] = __builtin_amdgcn_mfma_f32_16x16x32_bf16(
                    af[mt], bfr[nt], acc[mt][nt], 0, 0, 0);
    }

    __syncthreads();   // makes lA/lB/topo_s visible to all waves for the epilogue

    // epilogue: relu(sim - 1 + margin) over valid (li!=lj) upper-tri pairs, x2
    float local = 0.f;
#pragma unroll
    for (int mt = 0; mt < 4; ++mt) {
#pragma unroll
        for (int nt = 0; nt < 4; ++nt) {
#pragma unroll
            for (int reg = 0; reg < 4; ++reg) {
                int il = wrow + mt * 16 + quad * 4 + reg;
                int jl = wcol + nt * 16 + m16;
                int gi = ib0 + il, gj = jb0 + jl;
                int li = lA[il], lj = lB[jl];
                float v = acc[mt][nt][reg] - 1.0f + topo_s[li * C_N + lj];
                if (li != lj && gi < gj && v > 0.f) local += v;
            }
        }
    }
    local *= 2.0f;

#pragma unroll
    for (int off = 32; off; off >>= 1) local += __shfl_down(local, off, 64);
    if (lane == 0) wsum[w] = local;
    __syncthreads();
    if (t == 0) ws[8704 + bi * 32 + bj] = wsum[0] + wsum[1] + wsum[2] + wsum[3];
}

// ---------------- TALS + taml-partial reduce + final combine ----------------
__global__ void k_tals(const float* __restrict__ topo, float* __restrict__ ws,
                       float* __restrict__ out) {
    __shared__ float cents[C_N * D_N];   // 30 KB
    __shared__ float ed[112];
    __shared__ float cnt_s[C_N];
    __shared__ float wred[4];
    int t = threadIdx.x;   // 256 threads = 4 waves
    int w = t >> 6, lane = t & 63;

    // sum taml partials (upper-tri slots only)
    float tsum = 0.f;
    for (int idx = t; idx < 1024; idx += 256) {
        if ((idx & 31) >= (idx >> 5)) tsum += ws[8704 + idx];
    }
#pragma unroll
    for (int off = 32; off; off >>= 1) tsum += __shfl_xor(tsum, off, 64);
    if (lane == 0) wred[w] = tsum;

    if (t < C_N) cnt_s[t] = ws[8 + t];
    __syncthreads();
    for (int idx = t; idx < C_N * D_N; idx += 256) {
        int c = idx / D_N;
        cents[idx] = ws[32 + idx] / fmaxf(cnt_s[c], 1.0f);
    }
    __syncthreads();
    for (int pp = 0; pp < 25; ++pp) {   // 100 pairs; wave w: 25w..25w+24
        int p = w * 25 + pp;
        int i = p / C_N, j = p - (p / C_N) * C_N;
        const float* ci = cents + i * D_N;
        const float* cj = cents + j * D_N;
        float s = 0.f;
        for (int d = lane; d < D_N; d += 64) {
            float diff = ci[d] - cj[d];
            s += diff * diff;
        }
#pragma unroll
        for (int off = 32; off; off >>= 1) s += __shfl_xor(s, off, 64);
        if (lane == 0) ed[p] = sqrtf(s + 1e-12f);
    }
    __syncthreads();
    if (w == 0) {
        float e0 = ed[lane];
        float e1 = (lane < 36) ? ed[lane + 64] : 0.f;
        float mx = fmaxf(e0, e1);
#pragma unroll
        for (int off = 32; off; off >>= 1) mx = fmaxf(mx, __shfl_xor(mx, off, 64));
        float inv = 1.0f / (mx + 1e-8f);
        float d0 = e0 * inv - topo[lane];
        float s = d0 * d0;
        if (lane < 36) {
            float d1 = e1 * inv - topo[lane + 64];
            s += d1 * d1;
        }
#pragma unroll
        for (int off = 32; off; off >>= 1) s += __shfl_xor(s, off, 64);
        if (lane == 0) {
            float tals = s * (1.0f / (C_N * C_N));
            float s2 = 0.f;
#pragma unroll
            for (int c = 0; c < C_N; ++c) s2 += cnt_s[c] * cnt_s[c];
            float nvalid = (float)B_N * (float)B_N - s2;
            float ce   = ws[0] / (float)B_N;
            float taml = (wred[0] + wred[1] + wred[2] + wred[3]) / fmaxf(nvalid, 1.0f);
            out[0] = ce + 0.5f * tals + 0.5f * taml;
            out[1] = ce;
            out[2] = tals;
            out[3] = taml;
        }
    }
}

extern "C" void kernel_launch(void* const* d_in, const int* in_sizes, int n_in,
                              void* d_out, int out_size, void* d_ws, size_t ws_size,
                              hipStream_t stream) {
    const float* logits = (const float*)d_in[0];
    const int*   labels = (const int*)d_in[1];
    const float* emb    = (const float*)d_in[2];
    const float* topo   = (const float*)d_in[3];
    float* ws = (float*)d_ws;
    __hip_bfloat16* enorm = (__hip_bfloat16*)((char*)d_ws + 1048576);
    float* out = (float*)d_out;

    k_prep<<<1088, 256, 0, stream>>>(logits, labels, emb, ws, enorm);
    k_taml<<<dim3(32, 32), 256, 0, stream>>>(enorm, labels, topo, ws);
    k_tals<<<1, 256, 0, stream>>>(topo, ws, out);
}

// Round 11
// 147.259 us; speedup vs baseline: 1.4601x; 1.4601x over previous
//
#include <hip/hip_runtime.h>
#include <hip/hip_bf16.h>
#include <math.h>

#define B_N 4096
#define D_N 768
#define C_N 10

typedef short bf16x8 __attribute__((ext_vector_type(8)));
typedef float f32x4 __attribute__((ext_vector_type(4)));

// ws layout (floats):
//   [0] ce_sum   [1] taml_sum
//   [8..18)   counts[10]
//   [32..32+7680)  class sums [10][768]
// byte offset 65536: enorm bf16 [4096*768]  (6291456 bytes)

typedef __attribute__((address_space(1))) const void gvoid;
typedef __attribute__((address_space(3))) void lvoid;

static __device__ __forceinline__ void gl2lds16(const void* g, void* l) {
    // async global->LDS, 16B per lane, dest = l + lane*16 (wave-uniform l)
    __builtin_amdgcn_global_load_lds((gvoid*)g, (lvoid*)l, 16, 0, 0);
}

static __device__ __forceinline__ unsigned short bf16bits(float f, float s) {
    __hip_bfloat16 h = __float2bfloat16(f * s);
    return *(unsigned short*)&h;
}

// ---------------- merged prep: CE + histogram | class sums | row-normalize ----------------
// blocks [0,16): CE; [16,208): class segment sums; [208,1232): enorm (wave/row)
__global__ void k_prep(const float* __restrict__ logits,
                       const int* __restrict__ labels,
                       const float* __restrict__ emb,
                       float* __restrict__ ws,
                       __hip_bfloat16* __restrict__ enorm) {
    __shared__ float red[256];
    __shared__ float cnt[C_N];
    int bb = blockIdx.x;
    int t = threadIdx.x;

    if (bb < 16) {
        if (t < C_N) cnt[t] = 0.f;
        __syncthreads();
        int row = bb * 256 + t;
        int lab = labels[row];
        const float* lp = logits + (size_t)row * C_N;
        float m = lp[0];
#pragma unroll
        for (int c = 1; c < C_N; ++c) m = fmaxf(m, lp[c]);
        float s = 0.f;
#pragma unroll
        for (int c = 0; c < C_N; ++c) s += __expf(lp[c] - m);
        float val = (m + __logf(s)) - lp[lab];
        atomicAdd(&cnt[lab], 1.0f);
        red[t] = val;
        __syncthreads();
        for (int off = 128; off; off >>= 1) {
            if (t < off) red[t] += red[t + off];
            __syncthreads();
        }
        if (t == 0) atomicAdd(&ws[0], red[0]);
        if (t < C_N) atomicAdd(&ws[8 + t], cnt[t]);
    } else if (bb < 208) {
        int bx = (bb - 16) % 3, by = (bb - 16) / 3;
        int col = bx * 256 + t;
        int rbase = by * 64;
        float a[C_N];
#pragma unroll
        for (int c = 0; c < C_N; ++c) a[c] = 0.f;
        const float* p = emb + (size_t)rbase * D_N + col;
#pragma unroll 4
        for (int rr = 0; rr < 64; ++rr) {
            int lab = labels[rbase + rr];
            float v = p[(size_t)rr * D_N];
#pragma unroll
            for (int c = 0; c < C_N; ++c) a[c] += (lab == c) ? v : 0.f;
        }
        float* sums = ws + 32;
#pragma unroll
        for (int c = 0; c < C_N; ++c) atomicAdd(&sums[c * D_N + col], a[c]);
    } else {
        int w = t >> 6, lane = t & 63;
        int row = (bb - 208) * 4 + w;
        const float4* src = (const float4*)(emb + (size_t)row * D_N);
        float4 x0 = src[lane];
        float4 x1 = src[lane + 64];
        float4 x2 = src[lane + 128];
        float ss = x0.x * x0.x + x0.y * x0.y + x0.z * x0.z + x0.w * x0.w
                 + x1.x * x1.x + x1.y * x1.y + x1.z * x1.z + x1.w * x1.w
                 + x2.x * x2.x + x2.y * x2.y + x2.z * x2.z + x2.w * x2.w;
#pragma unroll
        for (int off = 32; off; off >>= 1) ss += __shfl_xor(ss, off, 64);
        float inv = 1.0f / fmaxf(sqrtf(ss), 1e-12f);
        ushort4* dst = (ushort4*)(enorm + (size_t)row * D_N);
        ushort4 u0, u1, u2;
        u0.x = bf16bits(x0.x, inv); u0.y = bf16bits(x0.y, inv);
        u0.z = bf16bits(x0.z, inv); u0.w = bf16bits(x0.w, inv);
        u1.x = bf16bits(x1.x, inv); u1.y = bf16bits(x1.y, inv);
        u1.z = bf16bits(x1.z, inv); u1.w = bf16bits(x1.w, inv);
        u2.x = bf16bits(x2.x, inv); u2.y = bf16bits(x2.y, inv);
        u2.z = bf16bits(x2.z, inv); u2.w = bf16bits(x2.w, inv);
        dst[lane]       = u0;
        dst[lane + 64]  = u1;
        dst[lane + 128] = u2;
    }
}

// ---------------- fused TAML GEMM ----------------
// 128x128 tile, BK=32, double-buffered LDS (2x16KB -> ~34KB total -> 4 blocks/CU),
// async global_load_lds (16B), ONE barrier per K-iter placed AFTER compute so the
// pre-barrier vmcnt(0) drain of next-tile loads is covered by this iteration's
// 16 MFMAs AND by 16 co-resident waves/CU of other blocks (m114 overlap).
// 2-bit XOR k-slot swizzle on (m16>>1): fragment ds_read_b128 = 2 lanes/bank (free).
__global__ __launch_bounds__(256) void k_taml(const __hip_bfloat16* __restrict__ E,
                                              const int* __restrict__ labels,
                                              const float* __restrict__ topo,
                                              float* __restrict__ ws) {
    int bi = blockIdx.y, bj = blockIdx.x;
    if (bj < bi) return;   // uniform exit, before any barrier

    __shared__ __align__(16) __hip_bfloat16 As[2][128 * 32];   // 2 x 8 KB
    __shared__ __align__(16) __hip_bfloat16 Bs[2][128 * 32];   // 2 x 8 KB
    __shared__ int lA[128], lB[128];
    __shared__ float topo_s[C_N * C_N];
    __shared__ float wsum[4];

    int t = threadIdx.x;
    int ib0 = bi * 128, jb0 = bj * 128;
    if (t < 128) lA[t] = labels[ib0 + t];
    else         lB[t - 128] = labels[jb0 + t - 128];
    if (t < C_N * C_N) topo_s[t] = topo[t];

    int w = t >> 6, lane = t & 63;
    int quad = lane >> 4, m16 = lane & 15;
    int wrow = (w >> 1) * 64, wcol = (w & 1) * 64;
    int qsw = (quad ^ ((m16 >> 1) & 3)) * 8;   // swizzled fragment k-slot (elems)

    f32x4 acc[4][4];
    f32x4 z = {0.f, 0.f, 0.f, 0.f};
#pragma unroll
    for (int mt = 0; mt < 4; ++mt)
#pragma unroll
        for (int nt = 0; nt < 4; ++nt) acc[mt][nt] = z;

    // staging: 8 chunks of 1KB per tile (chunk h = rows 16h..16h+15, full 32-elem rows).
    // wave w owns chunks {w, w+4}. lane: r = lane>>2 (row in chunk), c = lane&3
    // (16B k-slot); lane fetches global slot c^((r>>1)&3) -> LDS slot c swizzled.
    int rl = lane >> 2, cs = lane & 3;
    int csw = (cs ^ ((rl >> 1) & 3)) * 8;   // elems
    const __hip_bfloat16* gA[2];
    const __hip_bfloat16* gB[2];
    int ldsoff[2];
#pragma unroll
    for (int h = 0; h < 2; ++h) {
        int chunk = w + 4 * h;
        gA[h] = E + (size_t)(ib0 + chunk * 16 + rl) * D_N + csw;
        gB[h] = E + (size_t)(jb0 + chunk * 16 + rl) * D_N + csw;
        ldsoff[h] = chunk * 512;   // elems (1 KB per chunk)
    }

    // prologue: tile 0 -> buffer 0
#pragma unroll
    for (int h = 0; h < 2; ++h) {
        gl2lds16(gA[h], &As[0][ldsoff[h]]);
        gl2lds16(gB[h], &Bs[0][ldsoff[h]]);
    }
    __syncthreads();   // drain tile0 (full latency paid once); also covers lA/lB/topo_s

    for (int kt = 0; kt < 24; ++kt) {
        int cur = kt & 1, nxt = cur ^ 1;
        if (kt < 23) {
#pragma unroll
            for (int h = 0; h < 2; ++h) {
                gl2lds16(gA[h] + (kt + 1) * 32, &As[nxt][ldsoff[h]]);
                gl2lds16(gB[h] + (kt + 1) * 32, &Bs[nxt][ldsoff[h]]);
            }
        }
        bf16x8 af[4], bfr[4];
#pragma unroll
        for (int x = 0; x < 4; ++x) {
            af[x]  = *(const bf16x8*)(&As[cur][(wrow + x * 16 + m16) * 32 + qsw]);
            bfr[x] = *(const bf16x8*)(&Bs[cur][(wcol + x * 16 + m16) * 32 + qsw]);
        }
#pragma unroll
        for (int mt = 0; mt < 4; ++mt)
#pragma unroll
            for (int nt = 0; nt < 4; ++nt)
                acc[mt][nt] = __builtin_amdgcn_mfma_f32_16x16x32_bf16(
                    af[mt], bfr[nt], acc[mt][nt], 0, 0, 0);
        __syncthreads();   // drain of next-tile loads happens AFTER compute
    }

    // epilogue: relu(sim - 1 + margin) over valid (li!=lj) upper-tri pairs, x2
    float local = 0.f;
#pragma unroll
    for (int mt = 0; mt < 4; ++mt) {
#pragma unroll
        for (int nt = 0; nt < 4; ++nt) {
#pragma unroll
            for (int reg = 0; reg < 4; ++reg) {
                int il = wrow + mt * 16 + quad * 4 + reg;
                int jl = wcol + nt * 16 + m16;
                int gi = ib0 + il, gj = jb0 + jl;
                int li = lA[il], lj = lB[jl];
                float v = acc[mt][nt][reg] - 1.0f + topo_s[li * C_N + lj];
                if (li != lj && gi < gj && v > 0.f) local += v;
            }
        }
    }
    local *= 2.0f;

#pragma unroll
    for (int off = 32; off; off >>= 1) local += __shfl_down(local, off, 64);
    if (lane == 0) wsum[w] = local;
    __syncthreads();
    if (t == 0) atomicAdd(&ws[1], wsum[0] + wsum[1] + wsum[2] + wsum[3]);
}

// ---------------- TALS + nvalid + final combine ----------------
__global__ void k_tals(const float* __restrict__ topo, float* __restrict__ ws,
                       float* __restrict__ out) {
    __shared__ float cents[C_N * D_N];   // 30 KB
    __shared__ float ed[112];
    __shared__ float cnt_s[C_N];
    int t = threadIdx.x;   // 256 threads = 4 waves
    int w = t >> 6, lane = t & 63;
    const float* counts = ws + 8;
    const float* sums = ws + 32;
    if (t < C_N) cnt_s[t] = counts[t];
    __syncthreads();
    for (int idx = t; idx < C_N * D_N; idx += 256) {
        int c = idx / D_N;
        cents[idx] = sums[idx] / fmaxf(cnt_s[c], 1.0f);
    }
    __syncthreads();
    for (int pp = 0; pp < 25; ++pp) {   // 100 pairs; wave w: 25w..25w+24
        int p = w * 25 + pp;
        int i = p / C_N, j = p - (p / C_N) * C_N;
        const float* ci = cents + i * D_N;
        const float* cj = cents + j * D_N;
        float s = 0.f;
        for (int d = lane; d < D_N; d += 64) {
            float diff = ci[d] - cj[d];
            s += diff * diff;
        }
#pragma unroll
        for (int off = 32; off; off >>= 1) s += __shfl_xor(s, off, 64);
        if (lane == 0) ed[p] = sqrtf(s + 1e-12f);
    }
    __syncthreads();
    if (w == 0) {
        float e0 = ed[lane];
        float e1 = (lane < 36) ? ed[lane + 64] : 0.f;
        float mx = fmaxf(e0, e1);
#pragma unroll
        for (int off = 32; off; off >>= 1) mx = fmaxf(mx, __shfl_xor(mx, off, 64));
        float inv = 1.0f / (mx + 1e-8f);
        float d0 = e0 * inv - topo[lane];
        float s = d0 * d0;
        if (lane < 36) {
            float d1 = e1 * inv - topo[lane + 64];
            s += d1 * d1;
        }
#pragma unroll
        for (int off = 32; off; off >>= 1) s += __shfl_xor(s, off, 64);
        if (lane == 0) {
            float tals = s * (1.0f / (C_N * C_N));
            float s2 = 0.f;
#pragma unroll
            for (int c = 0; c < C_N; ++c) s2 += cnt_s[c] * cnt_s[c];
            float nvalid = (float)B_N * (float)B_N - s2;
            float ce   = ws[0] / (float)B_N;
            float taml = ws[1] / fmaxf(nvalid, 1.0f);
            out[0] = ce + 0.5f * tals + 0.5f * taml;
            out[1] = ce;
            out[2] = tals;
            out[3] = taml;
        }
    }
}

extern "C" void kernel_launch(void* const* d_in, const int* in_sizes, int n_in,
                              void* d_out, int out_size, void* d_ws, size_t ws_size,
                              hipStream_t stream) {
    const float* logits = (const float*)d_in[0];
    const int*   labels = (const int*)d_in[1];
    const float* emb    = (const float*)d_in[2];
    const float* topo   = (const float*)d_in[3];
    float* ws = (float*)d_ws;
    __hip_bfloat16* enorm = (__hip_bfloat16*)((char*)d_ws + 65536);
    float* out = (float*)d_out;

    hipMemsetAsync(d_ws, 0, 31232, stream);
    k_prep<<<1232, 256, 0, stream>>>(logits, labels, emb, ws, enorm);
    k_taml<<<dim3(32, 32), 256, 0, stream>>>(enorm, labels, topo, ws);
    k_tals<<<1, 256, 0, stream>>>(topo, ws, out);
}

// Round 12
// 138.453 us; speedup vs baseline: 1.5530x; 1.0636x over previous
//
#include <hip/hip_runtime.h>
#include <hip/hip_bf16.h>
#include <math.h>

#define B_N 4096
#define D_N 768
#define C_N 10

typedef float f32x4 __attribute__((ext_vector_type(4)));
typedef unsigned char uchar;

// ws layout (floats):
//   [0] ce_sum   [1] taml_sum
//   [8..18)   counts[10]
//   [32..32+7680)  class sums [10][768]
// byte offset 65536: enorm fp8 e4m3 [4096 rows x 768 B]  (3145728 bytes)

typedef __attribute__((address_space(1))) const void gvoid;
typedef __attribute__((address_space(3))) void lvoid;

static __device__ __forceinline__ void gl2lds16(const void* g, void* l) {
    // async global->LDS, 16B per lane, dest = l + lane*16 (wave-uniform l)
    __builtin_amdgcn_global_load_lds((gvoid*)g, (lvoid*)l, 16, 0, 0);
}

// ---------------- merged prep: CE + histogram | class sums | row-normalize->fp8 ----------------
// blocks [0,16): CE; [16,208): class segment sums; [208,1232): enorm (wave/row)
__global__ void k_prep(const float* __restrict__ logits,
                       const int* __restrict__ labels,
                       const float* __restrict__ emb,
                       float* __restrict__ ws,
                       uchar* __restrict__ enorm) {
    __shared__ float red[256];
    __shared__ float cnt[C_N];
    int bb = blockIdx.x;
    int t = threadIdx.x;

    if (bb < 16) {
        if (t < C_N) cnt[t] = 0.f;
        __syncthreads();
        int row = bb * 256 + t;
        int lab = labels[row];
        const float* lp = logits + (size_t)row * C_N;
        float m = lp[0];
#pragma unroll
        for (int c = 1; c < C_N; ++c) m = fmaxf(m, lp[c]);
        float s = 0.f;
#pragma unroll
        for (int c = 0; c < C_N; ++c) s += __expf(lp[c] - m);
        float val = (m + __logf(s)) - lp[lab];
        atomicAdd(&cnt[lab], 1.0f);
        red[t] = val;
        __syncthreads();
        for (int off = 128; off; off >>= 1) {
            if (t < off) red[t] += red[t + off];
            __syncthreads();
        }
        if (t == 0) atomicAdd(&ws[0], red[0]);
        if (t < C_N) atomicAdd(&ws[8 + t], cnt[t]);
    } else if (bb < 208) {
        int bx = (bb - 16) % 3, by = (bb - 16) / 3;
        int col = bx * 256 + t;
        int rbase = by * 64;
        float a[C_N];
#pragma unroll
        for (int c = 0; c < C_N; ++c) a[c] = 0.f;
        const float* p = emb + (size_t)rbase * D_N + col;
#pragma unroll 4
        for (int rr = 0; rr < 64; ++rr) {
            int lab = labels[rbase + rr];
            float v = p[(size_t)rr * D_N];
#pragma unroll
            for (int c = 0; c < C_N; ++c) a[c] += (lab == c) ? v : 0.f;
        }
        float* sums = ws + 32;
#pragma unroll
        for (int c = 0; c < C_N; ++c) atomicAdd(&sums[c * D_N + col], a[c]);
    } else {
        int w = t >> 6, lane = t & 63;
        int row = (bb - 208) * 4 + w;
        const float4* src = (const float4*)(emb + (size_t)row * D_N);
        float4 x0 = src[lane];
        float4 x1 = src[lane + 64];
        float4 x2 = src[lane + 128];
        float ss = x0.x * x0.x + x0.y * x0.y + x0.z * x0.z + x0.w * x0.w
                 + x1.x * x1.x + x1.y * x1.y + x1.z * x1.z + x1.w * x1.w
                 + x2.x * x2.x + x2.y * x2.y + x2.z * x2.z + x2.w * x2.w;
#pragma unroll
        for (int off = 32; off; off >>= 1) ss += __shfl_xor(ss, off, 64);
        float inv = 1.0f / fmaxf(sqrtf(ss), 1e-12f);
        // HW fp8 convert (pairs) -> 3 packed dwords = 12 fp8 per lane
        int p0 = 0, p1 = 0, p2 = 0;
        p0 = __builtin_amdgcn_cvt_pk_fp8_f32(x0.x * inv, x0.y * inv, p0, false);
        p0 = __builtin_amdgcn_cvt_pk_fp8_f32(x0.z * inv, x0.w * inv, p0, true);
        p1 = __builtin_amdgcn_cvt_pk_fp8_f32(x1.x * inv, x1.y * inv, p1, false);
        p1 = __builtin_amdgcn_cvt_pk_fp8_f32(x1.z * inv, x1.w * inv, p1, true);
        p2 = __builtin_amdgcn_cvt_pk_fp8_f32(x2.x * inv, x2.y * inv, p2, false);
        p2 = __builtin_amdgcn_cvt_pk_fp8_f32(x2.z * inv, x2.w * inv, p2, true);
        unsigned int* dst = (unsigned int*)(enorm + (size_t)row * D_N);
        dst[lane]       = (unsigned int)p0;
        dst[lane + 64]  = (unsigned int)p1;
        dst[lane + 128] = (unsigned int)p2;
    }
}

// ---------------- fused TAML GEMM (fp8) ----------------
// 128x128 tile, BK=64 (rows are 64 B in fp8), double-buffered LDS (2x8KB per side,
// ~34KB total), async global_load_lds 16B, ONE barrier per K-iter AFTER compute
// (R8-proven structure). 16B-slot XOR swizzle on (row&3).
__global__ __launch_bounds__(256) void k_taml(const uchar* __restrict__ E,
                                              const int* __restrict__ labels,
                                              const float* __restrict__ topo,
                                              float* __restrict__ ws) {
    int bi = blockIdx.y, bj = blockIdx.x;
    if (bj < bi) return;   // uniform exit, before any barrier

    __shared__ __align__(16) uchar As[2][8192];   // 128 rows x 64 B
    __shared__ __align__(16) uchar Bs[2][8192];
    __shared__ int lA[128], lB[128];
    __shared__ float topo_s[C_N * C_N];
    __shared__ float wsum[4];

    int t = threadIdx.x;
    int ib0 = bi * 128, jb0 = bj * 128;
    if (t < 128) lA[t] = labels[ib0 + t];
    else         lB[t - 128] = labels[jb0 + t - 128];
    if (t < C_N * C_N) topo_s[t] = topo[t];

    int w = t >> 6, lane = t & 63;
    int quad = lane >> 4, m16 = lane & 15;
    int wrow = (w >> 1) * 64, wcol = (w & 1) * 64;

    f32x4 acc[4][4];
    f32x4 z = {0.f, 0.f, 0.f, 0.f};
#pragma unroll
    for (int mt = 0; mt < 4; ++mt)
#pragma unroll
        for (int nt = 0; nt < 4; ++nt) acc[mt][nt] = z;

    // staging: 8 chunks of 1KB per tile (chunk = 16 rows x 64 B). wave w owns
    // chunks {w, w+4} of A and of B. lane: rl = lane>>2 (row in chunk),
    // hs = lane&3 (16B slot); lane fetches global slot hs^(rl&3) -> LDS slot hs.
    int rl = lane >> 2, hs = lane & 3;
    int hsw = (hs ^ (rl & 3)) * 16;   // global byte offset within row
    const uchar* gA[2];
    const uchar* gB[2];
    int ldsoff[2];
#pragma unroll
    for (int h = 0; h < 2; ++h) {
        int chunk = w + 4 * h;
        gA[h] = E + (size_t)(ib0 + chunk * 16 + rl) * D_N + hsw;
        gB[h] = E + (size_t)(jb0 + chunk * 16 + rl) * D_N + hsw;
        ldsoff[h] = chunk * 1024;
    }

    // prologue: tile 0 -> buffer 0
#pragma unroll
    for (int h = 0; h < 2; ++h) {
        gl2lds16(gA[h], &As[0][ldsoff[h]]);
        gl2lds16(gB[h], &Bs[0][ldsoff[h]]);
    }
    __syncthreads();   // drain tile0; also covers lA/lB/topo_s

    for (int kt = 0; kt < 12; ++kt) {
        int cur = kt & 1, nxt = cur ^ 1;
        if (kt < 11) {
#pragma unroll
            for (int h = 0; h < 2; ++h) {
                gl2lds16(gA[h] + (kt + 1) * 64, &As[nxt][ldsoff[h]]);
                gl2lds16(gB[h] + (kt + 1) * 64, &Bs[nxt][ldsoff[h]]);
            }
        }
#pragma unroll
        for (int ks = 0; ks < 2; ++ks) {
            int hfrag = ks * 2 + (quad >> 1);   // 16B slot of this k-octet
            int in8 = (quad & 1) * 8;           // 8B half within the slot
            long af[4], bfr[4];
#pragma unroll
            for (int x = 0; x < 4; ++x) {
                int rowA = wrow + x * 16 + m16;
                int rowB = wcol + x * 16 + m16;
                af[x]  = *(const long*)(&As[cur][rowA * 64 + ((hfrag ^ (rowA & 3)) * 16) + in8]);
                bfr[x] = *(const long*)(&Bs[cur][rowB * 64 + ((hfrag ^ (rowB & 3)) * 16) + in8]);
            }
#pragma unroll
            for (int mt = 0; mt < 4; ++mt)
#pragma unroll
                for (int nt = 0; nt < 4; ++nt)
                    acc[mt][nt] = __builtin_amdgcn_mfma_f32_16x16x32_fp8_fp8(
                        af[mt], bfr[nt], acc[mt][nt], 0, 0, 0);
        }
        __syncthreads();   // drain of next-tile loads happens AFTER compute
    }

    // epilogue: relu(sim - 1 + margin) over valid (li!=lj) upper-tri pairs, x2
    float local = 0.f;
#pragma unroll
    for (int mt = 0; mt < 4; ++mt) {
#pragma unroll
        for (int nt = 0; nt < 4; ++nt) {
#pragma unroll
            for (int reg = 0; reg < 4; ++reg) {
                int il = wrow + mt * 16 + quad * 4 + reg;
                int jl = wcol + nt * 16 + m16;
                int gi = ib0 + il, gj = jb0 + jl;
                int li = lA[il], lj = lB[jl];
                float v = acc[mt][nt][reg] - 1.0f + topo_s[li * C_N + lj];
                if (li != lj && gi < gj && v > 0.f) local += v;
            }
        }
    }
    local *= 2.0f;

#pragma unroll
    for (int off = 32; off; off >>= 1) local += __shfl_down(local, off, 64);
    if (lane == 0) wsum[w] = local;
    __syncthreads();
    if (t == 0) atomicAdd(&ws[1], wsum[0] + wsum[1] + wsum[2] + wsum[3]);
}

// ---------------- TALS + nvalid + final combine ----------------
__global__ void k_tals(const float* __restrict__ topo, float* __restrict__ ws,
                       float* __restrict__ out) {
    __shared__ float cents[C_N * D_N];   // 30 KB
    __shared__ float ed[112];
    __shared__ float cnt_s[C_N];
    int t = threadIdx.x;   // 256 threads = 4 waves
    int w = t >> 6, lane = t & 63;
    const float* counts = ws + 8;
    const float* sums = ws + 32;
    if (t < C_N) cnt_s[t] = counts[t];
    __syncthreads();
    for (int idx = t; idx < C_N * D_N; idx += 256) {
        int c = idx / D_N;
        cents[idx] = sums[idx] / fmaxf(cnt_s[c], 1.0f);
    }
    __syncthreads();
    for (int pp = 0; pp < 25; ++pp) {   // 100 pairs; wave w: 25w..25w+24
        int p = w * 25 + pp;
        int i = p / C_N, j = p - (p / C_N) * C_N;
        const float* ci = cents + i * D_N;
        const float* cj = cents + j * D_N;
        float s = 0.f;
        for (int d = lane; d < D_N; d += 64) {
            float diff = ci[d] - cj[d];
            s += diff * diff;
        }
#pragma unroll
        for (int off = 32; off; off >>= 1) s += __shfl_xor(s, off, 64);
        if (lane == 0) ed[p] = sqrtf(s + 1e-12f);
    }
    __syncthreads();
    if (w == 0) {
        float e0 = ed[lane];
        float e1 = (lane < 36) ? ed[lane + 64] : 0.f;
        float mx = fmaxf(e0, e1);
#pragma unroll
        for (int off = 32; off; off >>= 1) mx = fmaxf(mx, __shfl_xor(mx, off, 64));
        float inv = 1.0f / (mx + 1e-8f);
        float d0 = e0 * inv - topo[lane];
        float s = d0 * d0;
        if (lane < 36) {
            float d1 = e1 * inv - topo[lane + 64];
            s += d1 * d1;
        }
#pragma unroll
        for (int off = 32; off; off >>= 1) s += __shfl_xor(s, off, 64);
        if (lane == 0) {
            float tals = s * (1.0f / (C_N * C_N));
            float s2 = 0.f;
#pragma unroll
            for (int c = 0; c < C_N; ++c) s2 += cnt_s[c] * cnt_s[c];
            float nvalid = (float)B_N * (float)B_N - s2;
            float ce   = ws[0] / (float)B_N;
            float taml = ws[1] / fmaxf(nvalid, 1.0f);
            out[0] = ce + 0.5f * tals + 0.5f * taml;
            out[1] = ce;
            out[2] = tals;
            out[3] = taml;
        }
    }
}

extern "C" void kernel_launch(void* const* d_in, const int* in_sizes, int n_in,
                              void* d_out, int out_size, void* d_ws, size_t ws_size,
                              hipStream_t stream) {
    const float* logits = (const float*)d_in[0];
    const int*   labels = (const int*)d_in[1];
    const float* emb    = (const float*)d_in[2];
    const float* topo   = (const float*)d_in[3];
    float* ws = (float*)d_ws;
    uchar* enorm = (uchar*)d_ws + 65536;
    float* out = (float*)d_out;

    hipMemsetAsync(d_ws, 0, 31232, stream);
    k_prep<<<1232, 256, 0, stream>>>(logits, labels, emb, ws, enorm);
    k_taml<<<dim3(32, 32), 256, 0, stream>>>(enorm, labels, topo, ws);
    k_tals<<<1, 256, 0, stream>>>(topo, ws, out);
}

// Round 13
// 105.669 us; speedup vs baseline: 2.0348x; 1.3102x over previous
//
#include <hip/hip_runtime.h>
#include <hip/hip_bf16.h>
#include <math.h>

#define B_N 4096
#define D_N 768
#define C_N 10

typedef float f32x4 __attribute__((ext_vector_type(4)));
typedef unsigned char uchar;

// ws layout (floats):
//   [0] ce_sum   [1] taml_sum   [2] tals   [3] nvalid
//   [8..18)   counts[10]
//   [32..32+7680)  class sums [10][768]
// byte offset 65536: enorm fp8 e4m3 [4096 rows x 768 B]  (3145728 bytes)

typedef __attribute__((address_space(1))) const void gvoid;
typedef __attribute__((address_space(3))) void lvoid;

static __device__ __forceinline__ void gl2lds16(const void* g, void* l) {
    // async global->LDS, 16B per lane, dest = l + lane*16 (wave-uniform l)
    __builtin_amdgcn_global_load_lds((gvoid*)g, (lvoid*)l, 16, 0, 0);
}

// ---------------- merged prep: CE + histogram | class sums | row-normalize->fp8 ----------------
// blocks [0,16): CE; [16,208): class segment sums; [208,1232): enorm (wave/row)
__global__ void k_prep(const float* __restrict__ logits,
                       const int* __restrict__ labels,
                       const float* __restrict__ emb,
                       float* __restrict__ ws,
                       uchar* __restrict__ enorm) {
    __shared__ float red[256];
    __shared__ float cnt[C_N];
    int bb = blockIdx.x;
    int t = threadIdx.x;

    if (bb < 16) {
        if (t < C_N) cnt[t] = 0.f;
        __syncthreads();
        int row = bb * 256 + t;
        int lab = labels[row];
        const float* lp = logits + (size_t)row * C_N;
        float m = lp[0];
#pragma unroll
        for (int c = 1; c < C_N; ++c) m = fmaxf(m, lp[c]);
        float s = 0.f;
#pragma unroll
        for (int c = 0; c < C_N; ++c) s += __expf(lp[c] - m);
        float val = (m + __logf(s)) - lp[lab];
        atomicAdd(&cnt[lab], 1.0f);
        red[t] = val;
        __syncthreads();
        for (int off = 128; off; off >>= 1) {
            if (t < off) red[t] += red[t + off];
            __syncthreads();
        }
        if (t == 0) atomicAdd(&ws[0], red[0]);
        if (t < C_N) atomicAdd(&ws[8 + t], cnt[t]);
    } else if (bb < 208) {
        int bx = (bb - 16) % 3, by = (bb - 16) / 3;
        int col = bx * 256 + t;
        int rbase = by * 64;
        float a[C_N];
#pragma unroll
        for (int c = 0; c < C_N; ++c) a[c] = 0.f;
        const float* p = emb + (size_t)rbase * D_N + col;
#pragma unroll 4
        for (int rr = 0; rr < 64; ++rr) {
            int lab = labels[rbase + rr];
            float v = p[(size_t)rr * D_N];
#pragma unroll
            for (int c = 0; c < C_N; ++c) a[c] += (lab == c) ? v : 0.f;
        }
        float* sums = ws + 32;
#pragma unroll
        for (int c = 0; c < C_N; ++c) atomicAdd(&sums[c * D_N + col], a[c]);
    } else {
        int w = t >> 6, lane = t & 63;
        int row = (bb - 208) * 4 + w;
        const float4* src = (const float4*)(emb + (size_t)row * D_N);
        float4 x0 = src[lane];
        float4 x1 = src[lane + 64];
        float4 x2 = src[lane + 128];
        float ss = x0.x * x0.x + x0.y * x0.y + x0.z * x0.z + x0.w * x0.w
                 + x1.x * x1.x + x1.y * x1.y + x1.z * x1.z + x1.w * x1.w
                 + x2.x * x2.x + x2.y * x2.y + x2.z * x2.z + x2.w * x2.w;
#pragma unroll
        for (int off = 32; off; off >>= 1) ss += __shfl_xor(ss, off, 64);
        float inv = 1.0f / fmaxf(sqrtf(ss), 1e-12f);
        int p0 = 0, p1 = 0, p2 = 0;
        p0 = __builtin_amdgcn_cvt_pk_fp8_f32(x0.x * inv, x0.y * inv, p0, false);
        p0 = __builtin_amdgcn_cvt_pk_fp8_f32(x0.z * inv, x0.w * inv, p0, true);
        p1 = __builtin_amdgcn_cvt_pk_fp8_f32(x1.x * inv, x1.y * inv, p1, false);
        p1 = __builtin_amdgcn_cvt_pk_fp8_f32(x1.z * inv, x1.w * inv, p1, true);
        p2 = __builtin_amdgcn_cvt_pk_fp8_f32(x2.x * inv, x2.y * inv, p2, false);
        p2 = __builtin_amdgcn_cvt_pk_fp8_f32(x2.z * inv, x2.w * inv, p2, true);
        unsigned int* dst = (unsigned int*)(enorm + (size_t)row * D_N);
        dst[lane]       = (unsigned int)p0;
        dst[lane + 64]  = (unsigned int)p1;
        dst[lane + 128] = (unsigned int)p2;
    }
}

// ---------------- fused TAML GEMM (fp8, BK=128) + TALS in an idle helper block ----------------
// 128x128 tile, BK=128 (row = 128 B fp8), double-buffered LDS (2 x 16KB per side,
// 64KB -> 2 blocks/CU), async global_load_lds 16B, ONE barrier per K-iter AFTER
// compute: 64 MFMAs cover each pre-barrier vmcnt drain. 3-bit XOR slot swizzle
// (R8-verified): DMA lane fetches global 16B-slot (cs^rl) -> LDS slot cs;
// fragment read of global slot s of row r comes from LDS slot s^(r&7).
__global__ __launch_bounds__(256) void k_taml(const uchar* __restrict__ E,
                                              const int* __restrict__ labels,
                                              const float* __restrict__ topo,
                                              float* __restrict__ ws) {
    __shared__ __align__(16) uchar As[2][16384];
    __shared__ __align__(16) uchar Bs[2][16384];
    __shared__ int lA[128], lB[128];
    __shared__ float topo_s[C_N * C_N];
    __shared__ float wsum[4];
    __shared__ float ed[112];
    __shared__ float cnt_s[C_N];

    int bi = blockIdx.y, bj = blockIdx.x;
    int t = threadIdx.x;
    int w = t >> 6, lane = t & 63;

    if (bj < bi) {
        // ---- idle helper block computes TALS (k_prep outputs are ready) ----
        if (bi == 1 && bj == 0) {
            float* cents = (float*)&As[0][0];   // 30 KB scratch
            const float* sums = ws + 32;
            if (t < C_N) cnt_s[t] = ws[8 + t];
            __syncthreads();
            for (int idx = t; idx < C_N * D_N; idx += 256) {
                int c = idx / D_N;
                cents[idx] = sums[idx] / fmaxf(cnt_s[c], 1.0f);
            }
            __syncthreads();
            for (int pp = 0; pp < 25; ++pp) {   // 100 pairs; wave w: 25w..25w+24
                int p = w * 25 + pp;
                int i = p / C_N, j = p - (p / C_N) * C_N;
                const float* ci = cents + i * D_N;
                const float* cj = cents + j * D_N;
                float s = 0.f;
                for (int d = lane; d < D_N; d += 64) {
                    float diff = ci[d] - cj[d];
                    s += diff * diff;
                }
#pragma unroll
                for (int off = 32; off; off >>= 1) s += __shfl_xor(s, off, 64);
                if (lane == 0) ed[p] = sqrtf(s + 1e-12f);
            }
            __syncthreads();
            if (w == 0) {
                float e0 = ed[lane];
                float e1 = (lane < 36) ? ed[lane + 64] : 0.f;
                float mx = fmaxf(e0, e1);
#pragma unroll
                for (int off = 32; off; off >>= 1) mx = fmaxf(mx, __shfl_xor(mx, off, 64));
                float inv = 1.0f / (mx + 1e-8f);
                float d0 = e0 * inv - topo[lane];
                float s = d0 * d0;
                if (lane < 36) {
                    float d1 = e1 * inv - topo[lane + 64];
                    s += d1 * d1;
                }
#pragma unroll
                for (int off = 32; off; off >>= 1) s += __shfl_xor(s, off, 64);
                if (lane == 0) {
                    ws[2] = s * (1.0f / (C_N * C_N));
                    float s2 = 0.f;
#pragma unroll
                    for (int c = 0; c < C_N; ++c) s2 += cnt_s[c] * cnt_s[c];
                    ws[3] = (float)B_N * (float)B_N - s2;
                }
            }
        }
        return;
    }

    int ib0 = bi * 128, jb0 = bj * 128;
    if (t < 128) lA[t] = labels[ib0 + t];
    else         lB[t - 128] = labels[jb0 + t - 128];
    if (t < C_N * C_N) topo_s[t] = topo[t];

    int quad = lane >> 4, m16 = lane & 15;
    int wrow = (w >> 1) * 64, wcol = (w & 1) * 64;

    f32x4 acc[4][4];
    f32x4 z = {0.f, 0.f, 0.f, 0.f};
#pragma unroll
    for (int mt = 0; mt < 4; ++mt)
#pragma unroll
        for (int nt = 0; nt < 4; ++nt) acc[mt][nt] = z;

    // staging: 16 chunks of 1KB per tile side (chunk = 8 rows x 128 B).
    // wave w owns chunks {w, w+4, w+8, w+12} per side. lane: rl = lane>>3 (row
    // in chunk), cs = lane&7 (16B slot); fetch global slot cs^rl -> LDS slot cs.
    int rl = lane >> 3, cs = lane & 7;
    int csw = (cs ^ rl) * 16;   // byte offset within the 128B row
    const uchar* gA[4];
    const uchar* gB[4];
    int ldsoff[4];
#pragma unroll
    for (int h = 0; h < 4; ++h) {
        int chunk = w + 4 * h;
        gA[h] = E + (size_t)(ib0 + chunk * 8 + rl) * D_N + csw;
        gB[h] = E + (size_t)(jb0 + chunk * 8 + rl) * D_N + csw;
        ldsoff[h] = chunk * 1024;
    }

    // prologue: tile 0 -> buffer 0
#pragma unroll
    for (int h = 0; h < 4; ++h) {
        gl2lds16(gA[h], &As[0][ldsoff[h]]);
        gl2lds16(gB[h], &Bs[0][ldsoff[h]]);
    }
    __syncthreads();   // drain tile0; also covers lA/lB/topo_s

    for (int kt = 0; kt < 6; ++kt) {
        int cur = kt & 1, nxt = cur ^ 1;
        if (kt < 5) {
#pragma unroll
            for (int h = 0; h < 4; ++h) {
                gl2lds16(gA[h] + (kt + 1) * 128, &As[nxt][ldsoff[h]]);
                gl2lds16(gB[h] + (kt + 1) * 128, &Bs[nxt][ldsoff[h]]);
            }
        }
#pragma unroll
        for (int ks = 0; ks < 4; ++ks) {
            int s = ks * 2 + (quad >> 1);   // 16B slot of this k-octet
            int in8 = (quad & 1) * 8;       // 8B half within the slot
            long af[4], bfr[4];
#pragma unroll
            for (int x = 0; x < 4; ++x) {
                int rowA = wrow + x * 16 + m16;
                int rowB = wcol + x * 16 + m16;
                af[x]  = *(const long*)(&As[cur][rowA * 128 + ((s ^ (rowA & 7)) * 16) + in8]);
                bfr[x] = *(const long*)(&Bs[cur][rowB * 128 + ((s ^ (rowB & 7)) * 16) + in8]);
            }
#pragma unroll
            for (int mt = 0; mt < 4; ++mt)
#pragma unroll
                for (int nt = 0; nt < 4; ++nt)
                    acc[mt][nt] = __builtin_amdgcn_mfma_f32_16x16x32_fp8_fp8(
                        af[mt], bfr[nt], acc[mt][nt], 0, 0, 0);
        }
        __syncthreads();   // drain of next-tile loads happens AFTER compute
    }

    // epilogue: relu(sim - 1 + margin) over valid (li!=lj) upper-tri pairs, x2
    float local = 0.f;
#pragma unroll
    for (int mt = 0; mt < 4; ++mt) {
#pragma unroll
        for (int nt = 0; nt < 4; ++nt) {
#pragma unroll
            for (int reg = 0; reg < 4; ++reg) {
                int il = wrow + mt * 16 + quad * 4 + reg;
                int jl = wcol + nt * 16 + m16;
                int gi = ib0 + il, gj = jb0 + jl;
                int li = lA[il], lj = lB[jl];
                float v = acc[mt][nt][reg] - 1.0f + topo_s[li * C_N + lj];
                if (li != lj && gi < gj && v > 0.f) local += v;
            }
        }
    }
    local *= 2.0f;

#pragma unroll
    for (int off = 32; off; off >>= 1) local += __shfl_down(local, off, 64);
    if (lane == 0) wsum[w] = local;
    __syncthreads();
    if (t == 0) atomicAdd(&ws[1], wsum[0] + wsum[1] + wsum[2] + wsum[3]);
}

// ---------------- final combine (tals/nvalid precomputed by k_taml helper) ----------------
__global__ void k_final(const float* __restrict__ ws, float* __restrict__ out) {
    if (threadIdx.x == 0 && blockIdx.x == 0) {
        float ce   = ws[0] / (float)B_N;
        float tals = ws[2];
        float taml = ws[1] / fmaxf(ws[3], 1.0f);
        out[0] = ce + 0.5f * tals + 0.5f * taml;
        out[1] = ce;
        out[2] = tals;
        out[3] = taml;
    }
}

extern "C" void kernel_launch(void* const* d_in, const int* in_sizes, int n_in,
                              void* d_out, int out_size, void* d_ws, size_t ws_size,
                              hipStream_t stream) {
    const float* logits = (const float*)d_in[0];
    const int*   labels = (const int*)d_in[1];
    const float* emb    = (const float*)d_in[2];
    const float* topo   = (const float*)d_in[3];
    float* ws = (float*)d_ws;
    uchar* enorm = (uchar*)d_ws + 65536;
    float* out = (float*)d_out;

    hipMemsetAsync(d_ws, 0, 31232, stream);
    k_prep<<<1232, 256, 0, stream>>>(logits, labels, emb, ws, enorm);
    k_taml<<<dim3(32, 32), 256, 0, stream>>>(enorm, labels, topo, ws);
    k_final<<<1, 64, 0, stream>>>(ws, out);
}